// Round 9
// baseline (286.545 us; speedup 1.0000x reference)
//
#include <hip/hip_runtime.h>
#include <math.h>

#define LRELU(x) ((x) > 0.0f ? (x) : 0.2f * (x))

typedef __attribute__((ext_vector_type(8))) short bf16x8;
typedef __attribute__((ext_vector_type(4))) float floatx4;
typedef __attribute__((ext_vector_type(2))) float f32x2;

__device__ __forceinline__ ushort f2bf(float f) {
    union { float f; unsigned u; } v; v.f = f;
    unsigned r = (v.u + 0x7FFFu + ((v.u >> 16) & 1u)) >> 16;
    return (ushort)r;
}
// dword holding bf16[c] (low) and bf16[c+1] (high) -> f32x2 {c, c+1}
__device__ __forceinline__ f32x2 bfpair(unsigned w) {
    union { unsigned u; float f; } lo, hi;
    lo.u = w << 16; hi.u = w & 0xffff0000u;
    return (f32x2){lo.f, hi.f};
}

// ================= fused prep: XCD-partitioned CSR fill + cvt(feat->bf16) + pack B1 + pack B2 =================
// Bp1 [272][128]: cols 0..255 = W1^T, 256..259 = W1@att_src (4 heads), 260..263 = W1@att_dst, pad.
// Bp2 [144][256]: cols 0..127 = W2^T, 128 = W2@att_src, 129 = W2@att_dst, pad.
// CSR: col[dst*64 + slot] (ushort src), slot = atomicAdd(deg[dst]); E edges only —
// self-loops are implicit in the gather kernels (lane dgE takes src = n).
// Fill blocks dispatched FIRST (latency-bound: overlap with BW-bound cvt/pack behind them).
__global__ __launch_bounds__(256) void prep_kernel(
    const float* __restrict__ feat, const float* __restrict__ W1,
    const float* __restrict__ as1, const float* __restrict__ ad1,
    const float* __restrict__ W2, const float* __restrict__ as2,
    const float* __restrict__ ad2, const int* __restrict__ ei,
    ushort* __restrict__ featb, ushort* __restrict__ Bp1, ushort* __restrict__ Bp2,
    int* __restrict__ deg, ushort* __restrict__ col,
    int N, int E, int Npart, int b_fil, int b_cvt, int b_p1)
{
    const int b = blockIdx.x, t = threadIdx.x;
    if (b < b_fil) {
        const int fb = b;
        const int part = fb & 7;
        const int base = (fb >> 3) * 2048;
        const int lo = part * Npart;
        const int hi = min(N, lo + Npart);
        for (int q0 = 0; q0 < 8; q0 += 4) {
            int dsts[4]; bool val[4];
#pragma unroll
            for (int u = 0; u < 4; ++u) {
                int k = base + (q0 + u) * 256 + t;
                val[u] = k < E;
                if (val[u]) dsts[u] = ei[E + k];
            }
#pragma unroll
            for (int u = 0; u < 4; ++u) {
                if (val[u] && dsts[u] >= lo && dsts[u] < hi) {
                    int k = base + (q0 + u) * 256 + t;
                    int src = ei[k];
                    int slot = atomicAdd(&deg[dsts[u]], 1);
                    if (slot < 63) col[dsts[u] * 64 + slot] = (ushort)src;
                }
            }
        }
    } else if (b < b_fil + b_cvt) {
        int i = (b - b_fil) * 256 + t;
        if (i < N * 32) {
            float4 v = ((const float4*)feat)[i];
            ushort4 o;
            o.x = f2bf(v.x); o.y = f2bf(v.y); o.z = f2bf(v.z); o.w = f2bf(v.w);
            ((ushort4*)featb)[i] = o;
        }
    } else if (b < b_fil + b_cvt + b_p1) {
        int i = (b - b_fil - b_cvt) * 256 + t;
        if (i < 272 * 128) {
            int n = i / 128, k = i % 128;
            float v;
            if (n < 256) v = W1[k * 256 + n];
            else if (n < 260) {
                int h = n - 256; float s = 0.f;
                for (int c = 0; c < 64; ++c) s += W1[k * 256 + h * 64 + c] * as1[h * 64 + c];
                v = s;
            } else if (n < 264) {
                int h = n - 260; float s = 0.f;
                for (int c = 0; c < 64; ++c) s += W1[k * 256 + h * 64 + c] * ad1[h * 64 + c];
                v = s;
            } else v = 0.f;
            Bp1[i] = f2bf(v);
        }
    } else {
        int i = (b - b_fil - b_cvt - b_p1) * 256 + t;
        if (i < 144 * 256) {
            int n = i / 256, k = i % 256;
            float v;
            if (n < 128) v = W2[k * 128 + n];
            else if (n == 128) {
                float s = 0.f;
                for (int c = 0; c < 128; ++c) s += W2[k * 128 + c] * as2[c];
                v = s;
            } else if (n == 129) {
                float s = 0.f;
                for (int c = 0; c < 128; ++c) s += W2[k * 128 + c] * ad2[c];
                v = s;
            } else v = 0.f;
            Bp2[i] = f2bf(v);
        }
    }
}

// ================= skinny GEMM: layer-1 attention composites (cols 256..271 of Bp1) =================
__global__ __launch_bounds__(256) void gemm_attn1_kernel(
    const ushort* __restrict__ A, const ushort* __restrict__ Bp,
    float* __restrict__ as_, float* __restrict__ ad_, int M)
{
    const int lane = threadIdx.x & 63;
    const int wave = threadIdx.x >> 6;
    const int quad = lane >> 4;
    const int l16  = lane & 15;
    const int row0 = blockIdx.x * 64 + wave * 16;
    const int arow = min(row0 + l16, M - 1);
    const ushort* ap = A + (size_t)arow * 128 + quad * 8;
    const ushort* bp = Bp + (size_t)(256 + l16) * 128 + quad * 8;

    floatx4 acc = (floatx4){0.f, 0.f, 0.f, 0.f};
#pragma unroll
    for (int k0 = 0; k0 < 128; k0 += 32) {
        bf16x8 a = *(const bf16x8*)(ap + k0);
        bf16x8 b = *(const bf16x8*)(bp + k0);
        acc = __builtin_amdgcn_mfma_f32_16x16x32_bf16(a, b, acc, 0, 0, 0);
    }
#pragma unroll
    for (int r = 0; r < 4; ++r) {
        int row = row0 + quad * 4 + r;
        if (row < M) {
            float v = acc[r];
            if (l16 < 4)      as_[row * 4 + l16] = v;
            else if (l16 < 8) ad_[row * 4 + (l16 - 4)] = v;
        }
    }
}

// ================= FUSED layer-1: gather (x-space) -> W1 GEMM -> W2 GEMM, all in one block =================
// Rounds 3/4/6/8 proved hipcc collapses every source-level pipeline of the gather back to ~2
// loads in flight (VGPR 32-36); round-5's skeleton (50us) is the schedule floor. So: work
// reduction + phase overlap instead. Block = 16 dst rows, 4 waves.
// Phase A: wave w gathers nodes w*4..w*4+3 (round-5 body VERBATIM per node), writing the 4-head
//   aggregate to LDS agg[4][16][136] bf16 — eliminates the 50 MB aggx write + 25.6 MB re-read.
// Phase B: wave = head; x1[16 rows][64 cols] = LRELU(agg[w] @ W1_w + b1) -> x1s LDS.
// Phase C: col-split x1 @ Bp2 (9 16-col tiles; wave 3 takes tile 8 = as2/ad2 composites).
// Blocks at phase A (latency-bound) and B/C (MFMA) co-reside per CU -> GEMM hides under gathers.
// LDS 29.3 KB -> 5 blocks/CU -> 20 waves/CU.
__global__ __launch_bounds__(256) void gat_fused1_kernel(
    const int* __restrict__ deg, const ushort* __restrict__ col,
    const float* __restrict__ as_, const float* __restrict__ ad_,
    const ushort* __restrict__ xb, const ushort* __restrict__ Bp1,
    const float* __restrict__ bias1, const ushort* __restrict__ Bp2,
    ushort* __restrict__ h2b, float* __restrict__ as2_, float* __restrict__ ad2_, int N)
{
    __shared__ float4 alph[4][64];
    __shared__ __align__(16) ushort agg[4][16][136];   // [head][row][ch], +8 pad
    __shared__ __align__(16) ushort x1s[16][264];
    const int lane = threadIdx.x & 63;
    const int wave = threadIdx.x >> 6;
    const int quad = lane >> 4;
    const int l16  = lane & 15;
    const int brow = blockIdx.x * 16;
    const int esl = lane >> 5;
    const int ch0 = (lane & 31) * 4;

    // ---- phase A: 4 sequential gathers per wave (round-5 proven schedule) ----
    for (int i = 0; i < 4; ++i) {
        const int row = wave * 4 + i;
        const int n = brow + row;
        if (n < N) {
            const int dgE = min(deg[n], 63);
            const float4 ad4 = *(const float4*)(ad_ + n * 4);
            int src = n;                   // lane dgE = implicit self-loop
            float4 ex4 = {0.f, 0.f, 0.f, 0.f};
            if (lane <= dgE) {
                if (lane < dgE) src = col[n * 64 + lane];
                float4 a4 = *(const float4*)(as_ + src * 4);
                ex4.x = __expf(LRELU(a4.x + ad4.x));
                ex4.y = __expf(LRELU(a4.y + ad4.y));
                ex4.z = __expf(LRELU(a4.z + ad4.z));
                ex4.w = __expf(LRELU(a4.w + ad4.w));
                alph[wave][lane] = ex4;
            }
            float sx = ex4.x, sy = ex4.y, sz = ex4.z, sw = ex4.w;
#pragma unroll
            for (int m = 1; m < 64; m <<= 1) {
                sx += __shfl_xor(sx, m, 64); sy += __shfl_xor(sy, m, 64);
                sz += __shfl_xor(sz, m, 64); sw += __shfl_xor(sw, m, 64);
            }
            const float rd[4] = {1.0f / sx, 1.0f / sy, 1.0f / sz, 1.0f / sw};

            const int dg = dgE + 1;
            f32x2 accA[4] = {{0.f,0.f},{0.f,0.f},{0.f,0.f},{0.f,0.f}};
            f32x2 accB[4] = {{0.f,0.f},{0.f,0.f},{0.f,0.f},{0.f,0.f}};
            for (int j0 = 0; j0 < dg; j0 += 8) {
                uint2 u[4]; float4 a[4]; bool v[4]; int jj[4];
#pragma unroll
                for (int q = 0; q < 4; ++q) {
                    jj[q] = j0 + 2 * q + esl;
                    v[q] = jj[q] < dg;
                    if (v[q]) {
                        int s = __shfl(src, jj[q], 64);
                        a[q] = alph[wave][jj[q]];
                        u[q] = *(const uint2*)(xb + (size_t)s * 128 + ch0);
                    }
                }
#pragma unroll
                for (int q = 0; q < 4; ++q) {
                    if (v[q]) {
                        f32x2 xlo = bfpair(u[q].x), xhi = bfpair(u[q].y);
                        accA[0] += (f32x2){a[q].x, a[q].x} * xlo; accB[0] += (f32x2){a[q].x, a[q].x} * xhi;
                        accA[1] += (f32x2){a[q].y, a[q].y} * xlo; accB[1] += (f32x2){a[q].y, a[q].y} * xhi;
                        accA[2] += (f32x2){a[q].z, a[q].z} * xlo; accB[2] += (f32x2){a[q].z, a[q].z} * xhi;
                        accA[3] += (f32x2){a[q].w, a[q].w} * xlo; accB[3] += (f32x2){a[q].w, a[q].w} * xhi;
                    }
                }
            }
#pragma unroll
            for (int h = 0; h < 4; ++h) {
                accA[h].x += __shfl_xor(accA[h].x, 32, 64); accA[h].y += __shfl_xor(accA[h].y, 32, 64);
                accB[h].x += __shfl_xor(accB[h].x, 32, 64); accB[h].y += __shfl_xor(accB[h].y, 32, 64);
            }
            if (lane < 32) {
#pragma unroll
                for (int h = 0; h < 4; ++h) {
                    ushort4 o;
                    o.x = f2bf(accA[h].x * rd[h]); o.y = f2bf(accA[h].y * rd[h]);
                    o.z = f2bf(accB[h].x * rd[h]); o.w = f2bf(accB[h].y * rd[h]);
                    *(ushort4*)&agg[h][row][ch0] = o;
                }
            }
        } else if (lane < 32) {
            // zero-fill tail rows so the GEMM reads defined data
            ushort4 z = {0, 0, 0, 0};
#pragma unroll
            for (int h = 0; h < 4; ++h) *(ushort4*)&agg[h][row][ch0] = z;
        }
    }
    __syncthreads();

    // ---- phase B: x1[16][64 cols of head=wave] = LRELU(agg[wave] @ W1_wave + b1) ----
    {
        floatx4 acc[4];
#pragma unroll
        for (int nt = 0; nt < 4; ++nt) acc[nt] = (floatx4){0.f, 0.f, 0.f, 0.f};
#pragma unroll
        for (int kq = 0; kq < 4; ++kq) {
            bf16x8 a = *(const bf16x8*)&agg[wave][l16][kq * 32 + quad * 8];
#pragma unroll
            for (int nt = 0; nt < 4; ++nt) {
                bf16x8 b = *(const bf16x8*)(Bp1 + (size_t)(wave * 64 + nt * 16 + l16) * 128 + kq * 32 + quad * 8);
                acc[nt] = __builtin_amdgcn_mfma_f32_16x16x32_bf16(a, b, acc[nt], 0, 0, 0);
            }
        }
#pragma unroll
        for (int nt = 0; nt < 4; ++nt) {
            const int c = wave * 64 + nt * 16 + l16;
            const float bv = bias1[c];
#pragma unroll
            for (int r = 0; r < 4; ++r)
                x1s[quad * 4 + r][c] = f2bf(LRELU(acc[nt][r] + bv));
        }
    }
    __syncthreads();

    // ---- phase C: h2 (+composites) = x1 @ Bp2, col-split across waves ----
#pragma unroll
    for (int tt = 0; tt < 2; ++tt) {
        const int ct = wave * 2 + tt;
        bf16x8 bfr[8];
#pragma unroll
        for (int kq = 0; kq < 8; ++kq)
            bfr[kq] = *(const bf16x8*)(Bp2 + (size_t)(ct * 16 + l16) * 256 + kq * 32 + quad * 8);
        floatx4 acc = (floatx4){0.f, 0.f, 0.f, 0.f};
#pragma unroll
        for (int kq = 0; kq < 8; ++kq) {
            bf16x8 a = *(const bf16x8*)&x1s[l16][kq * 32 + quad * 8];
            acc = __builtin_amdgcn_mfma_f32_16x16x32_bf16(a, bfr[kq], acc, 0, 0, 0);
        }
#pragma unroll
        for (int r = 0; r < 4; ++r) {
            int row = brow + quad * 4 + r;
            if (row < N) h2b[(size_t)row * 128 + ct * 16 + l16] = f2bf(acc[r]);
        }
    }
    if (wave == 3) {                      // tile 8: attention composites
        bf16x8 bfr[8];
#pragma unroll
        for (int kq = 0; kq < 8; ++kq)
            bfr[kq] = *(const bf16x8*)(Bp2 + (size_t)(128 + l16) * 256 + kq * 32 + quad * 8);
        floatx4 acc = (floatx4){0.f, 0.f, 0.f, 0.f};
#pragma unroll
        for (int kq = 0; kq < 8; ++kq) {
            bf16x8 a = *(const bf16x8*)&x1s[l16][kq * 32 + quad * 8];
            acc = __builtin_amdgcn_mfma_f32_16x16x32_bf16(a, bfr[kq], acc, 0, 0, 0);
        }
#pragma unroll
        for (int r = 0; r < 4; ++r) {
            int row = brow + quad * 4 + r;
            if (row < N) {
                if (l16 == 0)      as2_[row] = acc[r];
                else if (l16 == 1) ad2_[row] = acc[r];
            }
        }
    }
}

// ================= layer-2 gather (H=1, C=128): round-5 skeleton + packed f32x2 consume =================
__global__ __launch_bounds__(256) void gat_gather2_kernel(
    const int* __restrict__ deg, const ushort* __restrict__ col,
    const float* __restrict__ as_, const float* __restrict__ ad_,
    const ushort* __restrict__ h2, const float* __restrict__ bias,
    const float* __restrict__ resid, float* __restrict__ out, int N)
{
    __shared__ float alph[4][64];
    const int lane = threadIdx.x & 63;
    const int wave = threadIdx.x >> 6;
    const int n = blockIdx.x * 4 + wave;
    if (n >= N) return;
    const int dgE = min(deg[n], 63);
    const float adv = ad_[n];

    int src = n;                    // lane dgE = implicit self-loop
    float ex = 0.f;
    if (lane <= dgE) {
        if (lane < dgE) src = col[n * 64 + lane];
        ex = __expf(LRELU(as_[src] + adv));
        alph[wave][lane] = ex;
    }
    float s = ex;
#pragma unroll
    for (int m = 1; m < 64; m <<= 1) s += __shfl_xor(s, m, 64);
    const float rden = 1.0f / s;

    const int esl = lane >> 5;
    const int ch0 = (lane & 31) * 4;
    const int dg = dgE + 1;
    f32x2 accA = {0.f, 0.f}, accB = {0.f, 0.f};

    for (int j0 = 0; j0 < dg; j0 += 8) {
        uint2 u[4]; float a[4]; bool v[4]; int jj[4];
#pragma unroll
        for (int q = 0; q < 4; ++q) {
            jj[q] = j0 + 2 * q + esl;
            v[q] = jj[q] < dg;
            if (v[q]) {
                int sA = __shfl(src, jj[q], 64);
                a[q] = alph[wave][jj[q]];
                u[q] = *(const uint2*)(h2 + (size_t)sA * 128 + ch0);
            }
        }
#pragma unroll
        for (int q = 0; q < 4; ++q) {
            if (v[q]) {
                accA += (f32x2){a[q], a[q]} * bfpair(u[q].x);
                accB += (f32x2){a[q], a[q]} * bfpair(u[q].y);
            }
        }
    }
    accA.x += __shfl_xor(accA.x, 32, 64); accA.y += __shfl_xor(accA.y, 32, 64);
    accB.x += __shfl_xor(accB.x, 32, 64); accB.y += __shfl_xor(accB.y, 32, 64);

    if (lane < 32) {
        const float4 bv = *(const float4*)(bias + ch0);
        const float4 fv = *(const float4*)(resid + (size_t)n * 128 + ch0);
        float4 o;
        o.x = LRELU(accA.x * rden + bv.x) + fv.x;
        o.y = LRELU(accA.y * rden + bv.y) + fv.y;
        o.z = LRELU(accB.x * rden + bv.z) + fv.z;
        o.w = LRELU(accB.y * rden + bv.w) + fv.w;
        *(float4*)(out + (size_t)n * 128 + ch0) = o;
    }
}

extern "C" void kernel_launch(void* const* d_in, const int* in_sizes, int n_in,
                              void* d_out, int out_size, void* d_ws, size_t ws_size,
                              hipStream_t stream)
{
    const float* feat = (const float*)d_in[0];
    const int*   ei   = (const int*)d_in[1];
    const float* W1   = (const float*)d_in[2];
    const float* asrc1 = (const float*)d_in[3];
    const float* adst1 = (const float*)d_in[4];
    const float* bias1 = (const float*)d_in[5];
    const float* W2    = (const float*)d_in[6];
    const float* asrc2 = (const float*)d_in[7];
    const float* adst2 = (const float*)d_in[8];
    const float* bias2 = (const float*)d_in[9];
    float* outp = (float*)d_out;

    const int IN_DIM = 128, C2 = 128;
    const int N = in_sizes[0] / IN_DIM;
    const int E = in_sizes[1] / 2;

    // workspace layout (bytes) — aggx eliminated by the fused kernel
    char* w = (char*)d_ws;
    ushort* featb = (ushort*)w; w += (size_t)N * IN_DIM * 2;     // 12.8 MB
    ushort* h2b   = (ushort*)w; w += (size_t)N * C2 * 2;         // 12.8 MB
    ushort* Bp1   = (ushort*)w; w += (size_t)272 * 128 * 2;
    ushort* Bp2   = (ushort*)w; w += (size_t)144 * 256 * 2;
    float* as1_   = (float*)w;  w += (size_t)N * 4 * 4;
    float* ad1_   = (float*)w;  w += (size_t)N * 4 * 4;
    float* as2_   = (float*)w;  w += (size_t)N * 4;
    float* ad2_   = (float*)w;  w += (size_t)N * 4;
    int* deg      = (int*)w;    w += (size_t)N * 4;
    ushort* col   = (ushort*)w; w += (size_t)N * 64 * 2;         // 6.4 MB padded CSR (ushort)

    dim3 blk(256);
    const int mg = (N + 63) / 64;
    const int fg = (N + 15) / 16;
    const int gg = (N + 3) / 4;
    const int Npart = (N + 7) / 8;

    const int b_cvt = (N * 32 + 255) / 256;
    const int b_p1  = (272 * 128 + 255) / 256;
    const int b_p2  = (144 * 256 + 255) / 256;
    const int b_fil = 8 * ((E + 2047) / 2048);   // 8 partitions x 2048-edge chunks (dispatched first)

    hipMemsetAsync(deg, 0, (size_t)N * 4, stream);
    prep_kernel<<<dim3(b_fil + b_cvt + b_p1 + b_p2), blk, 0, stream>>>(
        feat, W1, asrc1, adst1, W2, asrc2, adst2, ei,
        featb, Bp1, Bp2, deg, col, N, E, Npart, b_fil, b_cvt, b_p1);

    // ---- layer 1: composites ----
    gemm_attn1_kernel<<<dim3(mg), blk, 0, stream>>>(featb, Bp1, as1_, ad1_, N);

    // ---- FUSED: gather (x-space) + W1 GEMM + W2 GEMM ----
    gat_fused1_kernel<<<dim3(fg), blk, 0, stream>>>(
        deg, col, as1_, ad1_, featb, Bp1, bias1, Bp2, h2b, as2_, ad2_, N);

    // ---- layer-2 gather + residual ----
    gat_gather2_kernel<<<dim3(gg), blk, 0, stream>>>(deg, col, as2_, ad2_, h2b, bias2, feat, outp, N);
}

// Round 11
// 257.439 us; speedup vs baseline: 1.1131x; 1.1131x over previous
//
#include <hip/hip_runtime.h>
#include <math.h>

#define LRELU(x) ((x) > 0.0f ? (x) : 0.2f * (x))

typedef __attribute__((ext_vector_type(8))) short bf16x8;
typedef __attribute__((ext_vector_type(4))) float floatx4;
typedef __attribute__((ext_vector_type(2))) float f32x2;

__device__ __forceinline__ float bf2f(ushort u) {
    union { unsigned u; float f; } v; v.u = ((unsigned)u) << 16; return v.f;
}
__device__ __forceinline__ ushort f2bf(float f) {
    union { float f; unsigned u; } v; v.f = f;
    unsigned r = (v.u + 0x7FFFu + ((v.u >> 16) & 1u)) >> 16;
    return (ushort)r;
}
// dword holding bf16[c] (low) and bf16[c+1] (high) -> f32x2 {c, c+1}
__device__ __forceinline__ f32x2 bfpair(unsigned w) {
    union { unsigned u; float f; } lo, hi;
    lo.u = w << 16; hi.u = w & 0xffff0000u;
    return (f32x2){lo.f, hi.f};
}

// ================= fused prep: XCD-partitioned CSR fill + cvt(feat->bf16) + pack B1 + pack B2 =================
// Bp1 [272][128]: cols 0..255 = W1^T, 256..259 = W1@att_src (4 heads), 260..263 = W1@att_dst, pad.
// Bp2 [144][256]: cols 0..127 = W2^T, 128 = W2@att_src, 129 = W2@att_dst, pad.
// CSR: col[dst*64 + slot] (ushort src), slot = atomicAdd(deg[dst]); E edges only —
// self-loops are implicit in the gather kernels (lane dgE takes src = n).
// Fill blocks dispatched FIRST (latency-bound: overlap with BW-bound cvt/pack behind them).
// 1024-edge chunks (round-11: was 2048) -> 2x fill blocks -> more TLP for the atomic phase;
// dst-read redundancy is 8x regardless of chunk size, so traffic is unchanged.
__global__ __launch_bounds__(256) void prep_kernel(
    const float* __restrict__ feat, const float* __restrict__ W1,
    const float* __restrict__ as1, const float* __restrict__ ad1,
    const float* __restrict__ W2, const float* __restrict__ as2,
    const float* __restrict__ ad2, const int* __restrict__ ei,
    ushort* __restrict__ featb, ushort* __restrict__ Bp1, ushort* __restrict__ Bp2,
    int* __restrict__ deg, ushort* __restrict__ col,
    int N, int E, int Npart, int b_fil, int b_cvt, int b_p1)
{
    const int b = blockIdx.x, t = threadIdx.x;
    if (b < b_fil) {
        const int fb = b;
        const int part = fb & 7;
        const int base = (fb >> 3) * 1024;
        const int lo = part * Npart;
        const int hi = min(N, lo + Npart);
        int dsts[4]; bool val[4];
#pragma unroll
        for (int u = 0; u < 4; ++u) {
            int k = base + u * 256 + t;
            val[u] = k < E;
            if (val[u]) dsts[u] = ei[E + k];
        }
#pragma unroll
        for (int u = 0; u < 4; ++u) {
            if (val[u] && dsts[u] >= lo && dsts[u] < hi) {
                int k = base + u * 256 + t;
                int src = ei[k];
                int slot = atomicAdd(&deg[dsts[u]], 1);
                if (slot < 63) col[dsts[u] * 64 + slot] = (ushort)src;
            }
        }
    } else if (b < b_fil + b_cvt) {
        int i = (b - b_fil) * 256 + t;
        if (i < N * 32) {
            float4 v = ((const float4*)feat)[i];
            ushort4 o;
            o.x = f2bf(v.x); o.y = f2bf(v.y); o.z = f2bf(v.z); o.w = f2bf(v.w);
            ((ushort4*)featb)[i] = o;
        }
    } else if (b < b_fil + b_cvt + b_p1) {
        int i = (b - b_fil - b_cvt) * 256 + t;
        if (i < 272 * 128) {
            int n = i / 128, k = i % 128;
            float v;
            if (n < 256) v = W1[k * 256 + n];
            else if (n < 260) {
                int h = n - 256; float s = 0.f;
                for (int c = 0; c < 64; ++c) s += W1[k * 256 + h * 64 + c] * as1[h * 64 + c];
                v = s;
            } else if (n < 264) {
                int h = n - 260; float s = 0.f;
                for (int c = 0; c < 64; ++c) s += W1[k * 256 + h * 64 + c] * ad1[h * 64 + c];
                v = s;
            } else v = 0.f;
            Bp1[i] = f2bf(v);
        }
    } else {
        int i = (b - b_fil - b_cvt - b_p1) * 256 + t;
        if (i < 144 * 256) {
            int n = i / 256, k = i % 256;
            float v;
            if (n < 128) v = W2[k * 128 + n];
            else if (n == 128) {
                float s = 0.f;
                for (int c = 0; c < 128; ++c) s += W2[k * 128 + c] * as2[c];
                v = s;
            } else if (n == 129) {
                float s = 0.f;
                for (int c = 0; c < 128; ++c) s += W2[k * 128 + c] * ad2[c];
                v = s;
            } else v = 0.f;
            Bp2[i] = f2bf(v);
        }
    }
}

// ================= skinny GEMM: layer-1 attention composites (cols 256..271 of Bp1) =================
__global__ __launch_bounds__(256) void gemm_attn1_kernel(
    const ushort* __restrict__ A, const ushort* __restrict__ Bp,
    float* __restrict__ as_, float* __restrict__ ad_, int M)
{
    const int lane = threadIdx.x & 63;
    const int wave = threadIdx.x >> 6;
    const int quad = lane >> 4;
    const int l16  = lane & 15;
    const int row0 = blockIdx.x * 64 + wave * 16;
    const int arow = min(row0 + l16, M - 1);
    const ushort* ap = A + (size_t)arow * 128 + quad * 8;
    const ushort* bp = Bp + (size_t)(256 + l16) * 128 + quad * 8;

    floatx4 acc = (floatx4){0.f, 0.f, 0.f, 0.f};
#pragma unroll
    for (int k0 = 0; k0 < 128; k0 += 32) {
        bf16x8 a = *(const bf16x8*)(ap + k0);
        bf16x8 b = *(const bf16x8*)(bp + k0);
        acc = __builtin_amdgcn_mfma_f32_16x16x32_bf16(a, b, acc, 0, 0, 0);
    }
#pragma unroll
    for (int r = 0; r < 4; ++r) {
        int row = row0 + quad * 4 + r;
        if (row < M) {
            float v = acc[r];
            if (l16 < 4)      as_[row * 4 + l16] = v;
            else if (l16 < 8) ad_[row * 4 + (l16 - 4)] = v;
        }
    }
}

// ================= layer-1 gather v4 (round-5 PROVEN): round-2 skeleton + packed f32x2 consume =================
// aggx[h][n][c] = (1/den_h) * sum_j alpha^h_j * x[src_j][c].
// Half-wave esl handles neighbor 2q+esl; per neighbor a lane reads 4 channels as one uint2 (8 B).
// Load loop prefetches u[4] payloads AND a[4] alphas together (VGPR 36, 3.08 TB/s, 50.2 us —
// every deeper-pipeline/wider-load variant regressed or broke: rounds 3,4,6,8,9,10).
__global__ __launch_bounds__(256) void gat_gather1_kernel(
    const int* __restrict__ deg, const ushort* __restrict__ col,
    const float* __restrict__ as_, const float* __restrict__ ad_,
    const ushort* __restrict__ xb, ushort* __restrict__ aggx, int N)
{
    __shared__ float4 alph[4][64];
    const int lane = threadIdx.x & 63;
    const int wave = threadIdx.x >> 6;
    const int n = blockIdx.x * 4 + wave;
    if (n >= N) return;
    const int dgE = min(deg[n], 63);
    const float4 ad4 = *(const float4*)(ad_ + n * 4);

    int src = n;                       // lane dgE = implicit self-loop
    float4 ex4 = {0.f, 0.f, 0.f, 0.f};
    if (lane <= dgE) {
        if (lane < dgE) src = col[n * 64 + lane];
        float4 a4 = *(const float4*)(as_ + src * 4);
        ex4.x = __expf(LRELU(a4.x + ad4.x));
        ex4.y = __expf(LRELU(a4.y + ad4.y));
        ex4.z = __expf(LRELU(a4.z + ad4.z));
        ex4.w = __expf(LRELU(a4.w + ad4.w));
        alph[wave][lane] = ex4;
    }
    float sx = ex4.x, sy = ex4.y, sz = ex4.z, sw = ex4.w;
#pragma unroll
    for (int m = 1; m < 64; m <<= 1) {
        sx += __shfl_xor(sx, m, 64); sy += __shfl_xor(sy, m, 64);
        sz += __shfl_xor(sz, m, 64); sw += __shfl_xor(sw, m, 64);
    }
    const float rd0 = 1.0f / sx, rd1 = 1.0f / sy, rd2 = 1.0f / sz, rd3 = 1.0f / sw;

    const int esl = lane >> 5;
    const int ch0 = (lane & 31) * 4;
    const int dg = dgE + 1;
    f32x2 accA[4] = {{0.f,0.f},{0.f,0.f},{0.f,0.f},{0.f,0.f}};   // ch0,ch1 per head
    f32x2 accB[4] = {{0.f,0.f},{0.f,0.f},{0.f,0.f},{0.f,0.f}};   // ch2,ch3 per head

    for (int j0 = 0; j0 < dg; j0 += 8) {
        uint2 u[4]; float4 a[4]; bool v[4]; int jj[4];
#pragma unroll
        for (int q = 0; q < 4; ++q) {
            jj[q] = j0 + 2 * q + esl;
            v[q] = jj[q] < dg;
            if (v[q]) {
                int s = __shfl(src, jj[q], 64);
                a[q] = alph[wave][jj[q]];
                u[q] = *(const uint2*)(xb + (size_t)s * 128 + ch0);
            }
        }
#pragma unroll
        for (int q = 0; q < 4; ++q) {
            if (v[q]) {
                f32x2 xlo = bfpair(u[q].x), xhi = bfpair(u[q].y);
                accA[0] += (f32x2){a[q].x, a[q].x} * xlo; accB[0] += (f32x2){a[q].x, a[q].x} * xhi;
                accA[1] += (f32x2){a[q].y, a[q].y} * xlo; accB[1] += (f32x2){a[q].y, a[q].y} * xhi;
                accA[2] += (f32x2){a[q].z, a[q].z} * xlo; accB[2] += (f32x2){a[q].z, a[q].z} * xhi;
                accA[3] += (f32x2){a[q].w, a[q].w} * xlo; accB[3] += (f32x2){a[q].w, a[q].w} * xhi;
            }
        }
    }
#pragma unroll
    for (int h = 0; h < 4; ++h) {
        accA[h].x += __shfl_xor(accA[h].x, 32, 64); accA[h].y += __shfl_xor(accA[h].y, 32, 64);
        accB[h].x += __shfl_xor(accB[h].x, 32, 64); accB[h].y += __shfl_xor(accB[h].y, 32, 64);
    }

    if (lane < 32) {
        const float rd[4] = {rd0, rd1, rd2, rd3};
#pragma unroll
        for (int h = 0; h < 4; ++h) {
            ushort4 o;
            o.x = f2bf(accA[h].x * rd[h]); o.y = f2bf(accA[h].y * rd[h]);
            o.z = f2bf(accB[h].x * rd[h]); o.w = f2bf(accB[h].y * rd[h]);
            *(ushort4*)(aggx + ((size_t)h * N + n) * 128 + ch0) = o;
        }
    }
}

// ================= phase-2 column tile helper: 64 rows x 16 cols of x1s @ Bp2 =================
__device__ __forceinline__ void l2_tile(int ct, const ushort x1s[64][264],
    const ushort* __restrict__ Bp2, int brow, int M, int lane,
    ushort* __restrict__ h2b, float* __restrict__ as2_, float* __restrict__ ad2_)
{
    const int quad = lane >> 4;
    const int l16  = lane & 15;
    // preload the tile's 8 B fragments (read once per block -> L2-hot)
    bf16x8 bfr[8];
#pragma unroll
    for (int kq = 0; kq < 8; ++kq)
        bfr[kq] = *(const bf16x8*)(Bp2 + (size_t)(ct * 16 + l16) * 256 + kq * 32 + quad * 8);

    floatx4 acc[4];
#pragma unroll
    for (int rg = 0; rg < 4; ++rg) acc[rg] = (floatx4){0.f, 0.f, 0.f, 0.f};
#pragma unroll
    for (int kq = 0; kq < 8; ++kq) {
#pragma unroll
        for (int rg = 0; rg < 4; ++rg) {
            bf16x8 a = *(const bf16x8*)&x1s[rg * 16 + l16][kq * 32 + quad * 8];
            acc[rg] = __builtin_amdgcn_mfma_f32_16x16x32_bf16(a, bfr[kq], acc[rg], 0, 0, 0);
        }
    }
    if (ct < 8) {
#pragma unroll
        for (int rg = 0; rg < 4; ++rg)
#pragma unroll
            for (int r = 0; r < 4; ++r) {
                int row = brow + rg * 16 + quad * 4 + r;
                if (row < M) h2b[(size_t)row * 128 + ct * 16 + l16] = f2bf(acc[rg][r]);
            }
    } else {
#pragma unroll
        for (int rg = 0; rg < 4; ++rg)
#pragma unroll
            for (int r = 0; r < 4; ++r) {
                int row = brow + rg * 16 + quad * 4 + r;
                if (row < M) {
                    if (l16 == 0)      as2_[row] = acc[rg][r];
                    else if (l16 == 1) ad2_[row] = acc[rg][r];
                }
            }
    }
}

// ================= fused chained GEMM v2: x1 = LRELU(aggx@W1_h + b1) (LDS) -> h2 = x1@W2 (+as2/ad2) =================
// Block = 64 rows, 4 waves.
// Phase 1: wave w = head w over ALL 64 rows; B (head slice) and A preloaded into registers
// (32 independent 16B loads in flight). Phase 2: column-split — wave w owns col-tiles
// {2w,2w+1} (wave 3 also tile 8 = attention composites); Bp2 read ONCE per block.
__global__ __launch_bounds__(256) void gemm_l1l2_kernel(
    const ushort* __restrict__ aggx, const ushort* __restrict__ Bp1,
    const float* __restrict__ bias1, const ushort* __restrict__ Bp2,
    ushort* __restrict__ h2b, float* __restrict__ as2_, float* __restrict__ ad2_, int M)
{
    __shared__ ushort x1s[64][264];
    const int lane = threadIdx.x & 63;
    const int wave = threadIdx.x >> 6;   // = head index in phase 1
    const int quad = lane >> 4;
    const int l16  = lane & 15;
    const int brow = blockIdx.x * 64;

    // ---- phase 1: preload B (head slice) and A (4 row-tiles x 4 k-quads) ----
    bf16x8 bfr[4][4];                    // [nt][kq]
#pragma unroll
    for (int nt = 0; nt < 4; ++nt)
#pragma unroll
        for (int kq = 0; kq < 4; ++kq)
            bfr[nt][kq] = *(const bf16x8*)(Bp1 + (size_t)(wave * 64 + nt * 16 + l16) * 128 + kq * 32 + quad * 8);

    bf16x8 afr[4][4];                    // [rt][kq]
#pragma unroll
    for (int rt = 0; rt < 4; ++rt) {
        const int arow = min(brow + rt * 16 + l16, M - 1);
        const ushort* ap = aggx + ((size_t)wave * M + arow) * 128 + quad * 8;
#pragma unroll
        for (int kq = 0; kq < 4; ++kq)
            afr[rt][kq] = *(const bf16x8*)(ap + kq * 32);
    }

#pragma unroll
    for (int rt = 0; rt < 4; ++rt) {
        floatx4 acc[4];
#pragma unroll
        for (int nt = 0; nt < 4; ++nt) acc[nt] = (floatx4){0.f, 0.f, 0.f, 0.f};
#pragma unroll
        for (int kq = 0; kq < 4; ++kq)
#pragma unroll
            for (int nt = 0; nt < 4; ++nt)
                acc[nt] = __builtin_amdgcn_mfma_f32_16x16x32_bf16(afr[rt][kq], bfr[nt][kq], acc[nt], 0, 0, 0);
#pragma unroll
        for (int nt = 0; nt < 4; ++nt) {
            const int c = wave * 64 + nt * 16 + l16;
            const float bv = bias1[c];
#pragma unroll
            for (int r = 0; r < 4; ++r)
                x1s[rt * 16 + quad * 4 + r][c] = f2bf(LRELU(acc[nt][r] + bv));
        }
    }
    __syncthreads();

    // ---- phase 2: h2 (+composites) from LDS, column-split across waves ----
    l2_tile(wave * 2,     x1s, Bp2, brow, M, lane, h2b, as2_, ad2_);
    l2_tile(wave * 2 + 1, x1s, Bp2, brow, M, lane, h2b, as2_, ad2_);
    if (wave == 3)
        l2_tile(8,        x1s, Bp2, brow, M, lane, h2b, as2_, ad2_);
}

// ================= layer-2 gather v4 (round-5 PROVEN, H=1, C=128) =================
__global__ __launch_bounds__(256) void gat_gather2_kernel(
    const int* __restrict__ deg, const ushort* __restrict__ col,
    const float* __restrict__ as_, const float* __restrict__ ad_,
    const ushort* __restrict__ h2, const float* __restrict__ bias,
    const float* __restrict__ resid, float* __restrict__ out, int N)
{
    __shared__ float alph[4][64];
    const int lane = threadIdx.x & 63;
    const int wave = threadIdx.x >> 6;
    const int n = blockIdx.x * 4 + wave;
    if (n >= N) return;
    const int dgE = min(deg[n], 63);
    const float adv = ad_[n];

    int src = n;                    // lane dgE = implicit self-loop
    float ex = 0.f;
    if (lane <= dgE) {
        if (lane < dgE) src = col[n * 64 + lane];
        ex = __expf(LRELU(as_[src] + adv));
        alph[wave][lane] = ex;
    }
    float s = ex;
#pragma unroll
    for (int m = 1; m < 64; m <<= 1) s += __shfl_xor(s, m, 64);
    const float rden = 1.0f / s;

    const int esl = lane >> 5;
    const int ch0 = (lane & 31) * 4;
    const int dg = dgE + 1;
    f32x2 accA = {0.f, 0.f}, accB = {0.f, 0.f};

    for (int j0 = 0; j0 < dg; j0 += 8) {
        uint2 u[4]; float a[4]; bool v[4]; int jj[4];
#pragma unroll
        for (int q = 0; q < 4; ++q) {
            jj[q] = j0 + 2 * q + esl;
            v[q] = jj[q] < dg;
            if (v[q]) {
                int sA = __shfl(src, jj[q], 64);
                a[q] = alph[wave][jj[q]];
                u[q] = *(const uint2*)(h2 + (size_t)sA * 128 + ch0);
            }
        }
#pragma unroll
        for (int q = 0; q < 4; ++q) {
            if (v[q]) {
                accA += (f32x2){a[q], a[q]} * bfpair(u[q].x);
                accB += (f32x2){a[q], a[q]} * bfpair(u[q].y);
            }
        }
    }
    accA.x += __shfl_xor(accA.x, 32, 64); accA.y += __shfl_xor(accA.y, 32, 64);
    accB.x += __shfl_xor(accB.x, 32, 64); accB.y += __shfl_xor(accB.y, 32, 64);

    if (lane < 32) {
        const float4 bv = *(const float4*)(bias + ch0);
        const float4 fv = *(const float4*)(resid + (size_t)n * 128 + ch0);
        float4 o;
        o.x = LRELU(accA.x * rden + bv.x) + fv.x;
        o.y = LRELU(accA.y * rden + bv.y) + fv.y;
        o.z = LRELU(accB.x * rden + bv.z) + fv.z;
        o.w = LRELU(accB.y * rden + bv.w) + fv.w;
        *(float4*)(out + (size_t)n * 128 + ch0) = o;
    }
}

extern "C" void kernel_launch(void* const* d_in, const int* in_sizes, int n_in,
                              void* d_out, int out_size, void* d_ws, size_t ws_size,
                              hipStream_t stream)
{
    const float* feat = (const float*)d_in[0];
    const int*   ei   = (const int*)d_in[1];
    const float* W1   = (const float*)d_in[2];
    const float* asrc1 = (const float*)d_in[3];
    const float* adst1 = (const float*)d_in[4];
    const float* bias1 = (const float*)d_in[5];
    const float* W2    = (const float*)d_in[6];
    const float* asrc2 = (const float*)d_in[7];
    const float* adst2 = (const float*)d_in[8];
    const float* bias2 = (const float*)d_in[9];
    float* outp = (float*)d_out;

    const int IN_DIM = 128, C2 = 128;
    const int N = in_sizes[0] / IN_DIM;
    const int E = in_sizes[1] / 2;

    // workspace layout (bytes)
    char* w = (char*)d_ws;
    ushort* featb = (ushort*)w; w += (size_t)N * IN_DIM * 2;     // 12.8 MB
    ushort* aggx  = (ushort*)w; w += (size_t)4 * N * IN_DIM * 2; // 51.2 MB
    ushort* h2b   = (ushort*)w; w += (size_t)N * C2 * 2;         // 12.8 MB
    ushort* Bp1   = (ushort*)w; w += (size_t)272 * 128 * 2;
    ushort* Bp2   = (ushort*)w; w += (size_t)144 * 256 * 2;
    float* as1_   = (float*)w;  w += (size_t)N * 4 * 4;
    float* ad1_   = (float*)w;  w += (size_t)N * 4 * 4;
    float* as2_   = (float*)w;  w += (size_t)N * 4;
    float* ad2_   = (float*)w;  w += (size_t)N * 4;
    int* deg      = (int*)w;    w += (size_t)N * 4;
    ushort* col   = (ushort*)w; w += (size_t)N * 64 * 2;         // 6.4 MB padded CSR (ushort)

    dim3 blk(256);
    const int mg = (N + 63) / 64;
    const int gg = (N + 3) / 4;
    const int Npart = (N + 7) / 8;

    const int b_cvt = (N * 32 + 255) / 256;
    const int b_p1  = (272 * 128 + 255) / 256;
    const int b_p2  = (144 * 256 + 255) / 256;
    const int b_fil = 8 * ((E + 1023) / 1024);   // 8 partitions x 1024-edge chunks (dispatched first)

    hipMemsetAsync(deg, 0, (size_t)N * 4, stream);
    prep_kernel<<<dim3(b_fil + b_cvt + b_p1 + b_p2), blk, 0, stream>>>(
        feat, W1, asrc1, adst1, W2, asrc2, adst2, ei,
        featb, Bp1, Bp2, deg, col, N, E, Npart, b_fil, b_cvt, b_p1);

    // ---- layer 1: composites -> x-space gather ----
    gemm_attn1_kernel<<<dim3(mg), blk, 0, stream>>>(featb, Bp1, as1_, ad1_, N);
    gat_gather1_kernel<<<dim3(gg), blk, 0, stream>>>(deg, col, as1_, ad1_, featb, aggx, N);

    // ---- fused per-head GEMM + layer-2 GEMM (x1 internal to LDS) ----
    gemm_l1l2_kernel<<<dim3(mg), blk, 0, stream>>>(aggx, Bp1, bias1, Bp2, h2b, as2_, ad2_, N);

    // ---- layer-2 gather + residual ----
    gat_gather2_kernel<<<dim3(gg), blk, 0, stream>>>(deg, col, as2_, ad2_, h2b, bias2, feat, outp, N);
}

// Round 13
// 251.051 us; speedup vs baseline: 1.1414x; 1.0254x over previous
//
#include <hip/hip_runtime.h>
#include <math.h>

#define LRELU(x) ((x) > 0.0f ? (x) : 0.2f * (x))

typedef __attribute__((ext_vector_type(8))) short bf16x8;
typedef __attribute__((ext_vector_type(4))) float floatx4;
typedef __attribute__((ext_vector_type(2))) float f32x2;

__device__ __forceinline__ ushort f2bf(float f) {
    union { float f; unsigned u; } v; v.f = f;
    unsigned r = (v.u + 0x7FFFu + ((v.u >> 16) & 1u)) >> 16;
    return (ushort)r;
}
// dword holding bf16[c] (low) and bf16[c+1] (high) -> f32x2 {c, c+1}
__device__ __forceinline__ f32x2 bfpair(unsigned w) {
    union { unsigned u; float f; } lo, hi;
    lo.u = w << 16; hi.u = w & 0xffff0000u;
    return (f32x2){lo.f, hi.f};
}

// ================= fused prep: XCD-partitioned CSR fill + cvt(feat->bf16) + pack B1 + pack B2 =================
// Bp1 [272][128]: cols 0..255 = W1^T, 256..259 = W1@att_src (4 heads), 260..263 = W1@att_dst, pad.
// Bp2 [144][256]: cols 0..127 = W2^T, 128 = W2@att_src, 129 = W2@att_dst, pad.
// CSR: col[dst*64 + slot] (ushort src), slot = atomicAdd(deg[dst]); E edges only —
// self-loops are implicit in the gather kernels (lane dgE takes src = n).
// Fill blocks dispatched FIRST (latency-bound: overlap with BW-bound cvt/pack behind them).
__global__ __launch_bounds__(256) void prep_kernel(
    const float* __restrict__ feat, const float* __restrict__ W1,
    const float* __restrict__ as1, const float* __restrict__ ad1,
    const float* __restrict__ W2, const float* __restrict__ as2,
    const float* __restrict__ ad2, const int* __restrict__ ei,
    ushort* __restrict__ featb, ushort* __restrict__ Bp1, ushort* __restrict__ Bp2,
    int* __restrict__ deg, ushort* __restrict__ col,
    int N, int E, int Npart, int b_fil, int b_cvt, int b_p1)
{
    const int b = blockIdx.x, t = threadIdx.x;
    if (b < b_fil) {
        const int fb = b;
        const int part = fb & 7;
        const int base = (fb >> 3) * 1024;
        const int lo = part * Npart;
        const int hi = min(N, lo + Npart);
        int dsts[4]; bool val[4];
#pragma unroll
        for (int u = 0; u < 4; ++u) {
            int k = base + u * 256 + t;
            val[u] = k < E;
            if (val[u]) dsts[u] = ei[E + k];
        }
#pragma unroll
        for (int u = 0; u < 4; ++u) {
            if (val[u] && dsts[u] >= lo && dsts[u] < hi) {
                int k = base + u * 256 + t;
                int src = ei[k];
                int slot = atomicAdd(&deg[dsts[u]], 1);
                if (slot < 63) col[dsts[u] * 64 + slot] = (ushort)src;
            }
        }
    } else if (b < b_fil + b_cvt) {
        int i = (b - b_fil) * 256 + t;
        if (i < N * 32) {
            float4 v = ((const float4*)feat)[i];
            ushort4 o;
            o.x = f2bf(v.x); o.y = f2bf(v.y); o.z = f2bf(v.z); o.w = f2bf(v.w);
            ((ushort4*)featb)[i] = o;
        }
    } else if (b < b_fil + b_cvt + b_p1) {
        int i = (b - b_fil - b_cvt) * 256 + t;
        if (i < 272 * 128) {
            int n = i / 128, k = i % 128;
            float v;
            if (n < 256) v = W1[k * 256 + n];
            else if (n < 260) {
                int h = n - 256; float s = 0.f;
                for (int c = 0; c < 64; ++c) s += W1[k * 256 + h * 64 + c] * as1[h * 64 + c];
                v = s;
            } else if (n < 264) {
                int h = n - 260; float s = 0.f;
                for (int c = 0; c < 64; ++c) s += W1[k * 256 + h * 64 + c] * ad1[h * 64 + c];
                v = s;
            } else v = 0.f;
            Bp1[i] = f2bf(v);
        }
    } else {
        int i = (b - b_fil - b_cvt - b_p1) * 256 + t;
        if (i < 144 * 256) {
            int n = i / 256, k = i % 256;
            float v;
            if (n < 128) v = W2[k * 128 + n];
            else if (n == 128) {
                float s = 0.f;
                for (int c = 0; c < 128; ++c) s += W2[k * 128 + c] * as2[c];
                v = s;
            } else if (n == 129) {
                float s = 0.f;
                for (int c = 0; c < 128; ++c) s += W2[k * 128 + c] * ad2[c];
                v = s;
            } else v = 0.f;
            Bp2[i] = f2bf(v);
        }
    }
}

// ================= skinny GEMM: layer-1 attention composites (cols 256..271 of Bp1) =================
__global__ __launch_bounds__(256) void gemm_attn1_kernel(
    const ushort* __restrict__ A, const ushort* __restrict__ Bp,
    float* __restrict__ as_, float* __restrict__ ad_, int M)
{
    const int lane = threadIdx.x & 63;
    const int wave = threadIdx.x >> 6;
    const int quad = lane >> 4;
    const int l16  = lane & 15;
    const int row0 = blockIdx.x * 64 + wave * 16;
    const int arow = min(row0 + l16, M - 1);
    const ushort* ap = A + (size_t)arow * 128 + quad * 8;
    const ushort* bp = Bp + (size_t)(256 + l16) * 128 + quad * 8;

    floatx4 acc = (floatx4){0.f, 0.f, 0.f, 0.f};
#pragma unroll
    for (int k0 = 0; k0 < 128; k0 += 32) {
        bf16x8 a = *(const bf16x8*)(ap + k0);
        bf16x8 b = *(const bf16x8*)(bp + k0);
        acc = __builtin_amdgcn_mfma_f32_16x16x32_bf16(a, b, acc, 0, 0, 0);
    }
#pragma unroll
    for (int r = 0; r < 4; ++r) {
        int row = row0 + quad * 4 + r;
        if (row < M) {
            float v = acc[r];
            if (l16 < 4)      as_[row * 4 + l16] = v;
            else if (l16 < 8) ad_[row * 4 + (l16 - 4)] = v;
        }
    }
}

// ================= layer-1 gather v10: batch-synchronous asm loads (vmcnt(0) drain) =================
// aggx[h][n][c] = (1/den_h) * sum_j alpha^h_j * x[src_j][c].
// Round-12's counted vmcnt(4) broke: compiler spill buffer_ops between asm blocks corrupt the
// count. This version is count-immune: issue 8 asm loads (j-step 16; max jj = j0+15 <= 63 so NO
// overshoot/clamp logic), then ONE `s_waitcnt vmcnt(0)` (waits everything incl. spills) +
// sched_barrier(0) (rule-18 fence), then consume all 8 branchless (alpha=0 beyond dgE).
// 8 loads in flight per batch vs the compiler's ~2 -> 1 latency exposure per 16 neighbors.
__global__ __launch_bounds__(256) void gat_gather1_kernel(
    const int* __restrict__ deg, const ushort* __restrict__ col,
    const float* __restrict__ as_, const float* __restrict__ ad_,
    const ushort* __restrict__ xb, ushort* __restrict__ aggx, int N)
{
    __shared__ float4 alph[4][64];
    const int lane = threadIdx.x & 63;
    const int wave = threadIdx.x >> 6;
    const int n = blockIdx.x * 4 + wave;
    if (n >= N) return;
    const int dgE = min(deg[n], 63);
    const float4 ad4 = *(const float4*)(ad_ + n * 4);

    int src = n;                       // lane dgE = implicit self-loop; default n for lanes > dgE
    float4 ex4 = {0.f, 0.f, 0.f, 0.f};
    if (lane <= dgE) {
        if (lane < dgE) src = col[n * 64 + lane];
        float4 a4 = *(const float4*)(as_ + src * 4);
        ex4.x = __expf(LRELU(a4.x + ad4.x));
        ex4.y = __expf(LRELU(a4.y + ad4.y));
        ex4.z = __expf(LRELU(a4.z + ad4.z));
        ex4.w = __expf(LRELU(a4.w + ad4.w));
    }
    alph[wave][lane] = ex4;            // zeros beyond dgE -> branchless consume
    float sx = ex4.x, sy = ex4.y, sz = ex4.z, sw = ex4.w;
#pragma unroll
    for (int m = 1; m < 64; m <<= 1) {
        sx += __shfl_xor(sx, m, 64); sy += __shfl_xor(sy, m, 64);
        sz += __shfl_xor(sz, m, 64); sw += __shfl_xor(sw, m, 64);
    }
    const float rd0 = 1.0f / sx, rd1 = 1.0f / sy, rd2 = 1.0f / sz, rd3 = 1.0f / sw;

    const int esl = lane >> 5;
    const int ch0 = (lane & 31) * 4;
    const int dg = dgE + 1;
    const int dgR = (dg + 15) & ~15;   // padded to j-step; alpha=0 covers [dg, dgR); dgR <= 64
    f32x2 accA[4] = {{0.f,0.f},{0.f,0.f},{0.f,0.f},{0.f,0.f}};   // ch0,ch1 per head
    f32x2 accB[4] = {{0.f,0.f},{0.f,0.f},{0.f,0.f},{0.f,0.f}};   // ch2,ch3 per head

    uint2 u1[4], u2[4];

#define G1_LOAD4(jb, u)                                                       \
    {                                                                         \
        _Pragma("unroll")                                                     \
        for (int q = 0; q < 4; ++q) {                                         \
            int jj = (jb) + 2 * q + esl;       /* jj <= j0+15 <= 63 */        \
            int s_ = __shfl(src, jj, 64);                                     \
            const ushort* p_ = xb + (size_t)s_ * 128 + ch0;                   \
            asm volatile("global_load_dwordx2 %0, %1, off"                    \
                         : "=v"(u[q]) : "v"(p_));                             \
        }                                                                     \
    }
#define G1_CONS4(jb, u)                                                       \
    {                                                                         \
        _Pragma("unroll")                                                     \
        for (int q = 0; q < 4; ++q) {                                         \
            int jj = (jb) + 2 * q + esl;                                      \
            float4 a = alph[wave][jj];                                        \
            f32x2 xlo = bfpair(u[q].x), xhi = bfpair(u[q].y);                 \
            accA[0] += (f32x2){a.x, a.x} * xlo; accB[0] += (f32x2){a.x, a.x} * xhi; \
            accA[1] += (f32x2){a.y, a.y} * xlo; accB[1] += (f32x2){a.y, a.y} * xhi; \
            accA[2] += (f32x2){a.z, a.z} * xlo; accB[2] += (f32x2){a.z, a.z} * xhi; \
            accA[3] += (f32x2){a.w, a.w} * xlo; accB[3] += (f32x2){a.w, a.w} * xhi; \
        }                                                                     \
    }

    for (int j0 = 0; j0 < dgR; j0 += 16) {
        G1_LOAD4(j0, u1);
        G1_LOAD4(j0 + 8, u2);          // 8 loads in flight
        asm volatile("s_waitcnt vmcnt(0)" ::: "memory");
        __builtin_amdgcn_sched_barrier(0);
        G1_CONS4(j0, u1);
        G1_CONS4(j0 + 8, u2);
    }

#pragma unroll
    for (int h = 0; h < 4; ++h) {
        accA[h].x += __shfl_xor(accA[h].x, 32, 64); accA[h].y += __shfl_xor(accA[h].y, 32, 64);
        accB[h].x += __shfl_xor(accB[h].x, 32, 64); accB[h].y += __shfl_xor(accB[h].y, 32, 64);
    }

    if (lane < 32) {
        const float rd[4] = {rd0, rd1, rd2, rd3};
#pragma unroll
        for (int h = 0; h < 4; ++h) {
            ushort4 o;
            o.x = f2bf(accA[h].x * rd[h]); o.y = f2bf(accA[h].y * rd[h]);
            o.z = f2bf(accB[h].x * rd[h]); o.w = f2bf(accB[h].y * rd[h]);
            *(ushort4*)(aggx + ((size_t)h * N + n) * 128 + ch0) = o;
        }
    }
}

// ================= phase-2 column tile helper: 64 rows x 16 cols of x1s @ Bp2 =================
__device__ __forceinline__ void l2_tile(int ct, const ushort x1s[64][264],
    const ushort* __restrict__ Bp2, int brow, int M, int lane,
    ushort* __restrict__ h2b, float* __restrict__ as2_, float* __restrict__ ad2_)
{
    const int quad = lane >> 4;
    const int l16  = lane & 15;
    // preload the tile's 8 B fragments (read once per block -> L2-hot)
    bf16x8 bfr[8];
#pragma unroll
    for (int kq = 0; kq < 8; ++kq)
        bfr[kq] = *(const bf16x8*)(Bp2 + (size_t)(ct * 16 + l16) * 256 + kq * 32 + quad * 8);

    floatx4 acc[4];
#pragma unroll
    for (int rg = 0; rg < 4; ++rg) acc[rg] = (floatx4){0.f, 0.f, 0.f, 0.f};
#pragma unroll
    for (int kq = 0; kq < 8; ++kq) {
#pragma unroll
        for (int rg = 0; rg < 4; ++rg) {
            bf16x8 a = *(const bf16x8*)&x1s[rg * 16 + l16][kq * 32 + quad * 8];
            acc[rg] = __builtin_amdgcn_mfma_f32_16x16x32_bf16(a, bfr[kq], acc[rg], 0, 0, 0);
        }
    }
    if (ct < 8) {
#pragma unroll
        for (int rg = 0; rg < 4; ++rg)
#pragma unroll
            for (int r = 0; r < 4; ++r) {
                int row = brow + rg * 16 + quad * 4 + r;
                if (row < M) h2b[(size_t)row * 128 + ct * 16 + l16] = f2bf(acc[rg][r]);
            }
    } else {
#pragma unroll
        for (int rg = 0; rg < 4; ++rg)
#pragma unroll
            for (int r = 0; r < 4; ++r) {
                int row = brow + rg * 16 + quad * 4 + r;
                if (row < M) {
                    if (l16 == 0)      as2_[row] = acc[rg][r];
                    else if (l16 == 1) ad2_[row] = acc[rg][r];
                }
            }
    }
}

// ================= fused chained GEMM v2: x1 = LRELU(aggx@W1_h + b1) (LDS) -> h2 = x1@W2 (+as2/ad2) =================
// Block = 64 rows, 4 waves.
// Phase 1: wave w = head w over ALL 64 rows; B (head slice) and A preloaded into registers
// (32 independent 16B loads in flight). Phase 2: column-split — wave w owns col-tiles
// {2w,2w+1} (wave 3 also tile 8 = attention composites); Bp2 read ONCE per block.
__global__ __launch_bounds__(256) void gemm_l1l2_kernel(
    const ushort* __restrict__ aggx, const ushort* __restrict__ Bp1,
    const float* __restrict__ bias1, const ushort* __restrict__ Bp2,
    ushort* __restrict__ h2b, float* __restrict__ as2_, float* __restrict__ ad2_, int M)
{
    __shared__ ushort x1s[64][264];
    const int lane = threadIdx.x & 63;
    const int wave = threadIdx.x >> 6;   // = head index in phase 1
    const int quad = lane >> 4;
    const int l16  = lane & 15;
    const int brow = blockIdx.x * 64;

    // ---- phase 1: preload B (head slice) and A (4 row-tiles x 4 k-quads) ----
    bf16x8 bfr[4][4];                    // [nt][kq]
#pragma unroll
    for (int nt = 0; nt < 4; ++nt)
#pragma unroll
        for (int kq = 0; kq < 4; ++kq)
            bfr[nt][kq] = *(const bf16x8*)(Bp1 + (size_t)(wave * 64 + nt * 16 + l16) * 128 + kq * 32 + quad * 8);

    bf16x8 afr[4][4];                    // [rt][kq]
#pragma unroll
    for (int rt = 0; rt < 4; ++rt) {
        const int arow = min(brow + rt * 16 + l16, M - 1);
        const ushort* ap = aggx + ((size_t)wave * M + arow) * 128 + quad * 8;
#pragma unroll
        for (int kq = 0; kq < 4; ++kq)
            afr[rt][kq] = *(const bf16x8*)(ap + kq * 32);
    }

#pragma unroll
    for (int rt = 0; rt < 4; ++rt) {
        floatx4 acc[4];
#pragma unroll
        for (int nt = 0; nt < 4; ++nt) acc[nt] = (floatx4){0.f, 0.f, 0.f, 0.f};
#pragma unroll
        for (int kq = 0; kq < 4; ++kq)
#pragma unroll
            for (int nt = 0; nt < 4; ++nt)
                acc[nt] = __builtin_amdgcn_mfma_f32_16x16x32_bf16(afr[rt][kq], bfr[nt][kq], acc[nt], 0, 0, 0);
#pragma unroll
        for (int nt = 0; nt < 4; ++nt) {
            const int c = wave * 64 + nt * 16 + l16;
            const float bv = bias1[c];
#pragma unroll
            for (int r = 0; r < 4; ++r)
                x1s[rt * 16 + quad * 4 + r][c] = f2bf(LRELU(acc[nt][r] + bv));
        }
    }
    __syncthreads();

    // ---- phase 2: h2 (+composites) from LDS, column-split across waves ----
    l2_tile(wave * 2,     x1s, Bp2, brow, M, lane, h2b, as2_, ad2_);
    l2_tile(wave * 2 + 1, x1s, Bp2, brow, M, lane, h2b, as2_, ad2_);
    if (wave == 3)
        l2_tile(8,        x1s, Bp2, brow, M, lane, h2b, as2_, ad2_);
}

// ================= layer-2 gather v10 (H=1, C=128): batch-synchronous asm loads =================
__global__ __launch_bounds__(256) void gat_gather2_kernel(
    const int* __restrict__ deg, const ushort* __restrict__ col,
    const float* __restrict__ as_, const float* __restrict__ ad_,
    const ushort* __restrict__ h2, const float* __restrict__ bias,
    const float* __restrict__ resid, float* __restrict__ out, int N)
{
    __shared__ float alph[4][64];
    const int lane = threadIdx.x & 63;
    const int wave = threadIdx.x >> 6;
    const int n = blockIdx.x * 4 + wave;
    if (n >= N) return;
    const int dgE = min(deg[n], 63);
    const float adv = ad_[n];

    int src = n;                    // lane dgE = implicit self-loop; default n beyond dgE
    float ex = 0.f;
    if (lane <= dgE) {
        if (lane < dgE) src = col[n * 64 + lane];
        ex = __expf(LRELU(as_[src] + adv));
    }
    alph[wave][lane] = ex;          // zeros beyond dgE
    float s = ex;
#pragma unroll
    for (int m = 1; m < 64; m <<= 1) s += __shfl_xor(s, m, 64);
    const float rden = 1.0f / s;

    const int esl = lane >> 5;
    const int ch0 = (lane & 31) * 4;
    const int dg = dgE + 1;
    const int dgR = (dg + 15) & ~15;
    f32x2 accA = {0.f, 0.f}, accB = {0.f, 0.f};

    uint2 u1[4], u2[4];

#define G2_LOAD4(jb, u)                                                       \
    {                                                                         \
        _Pragma("unroll")                                                     \
        for (int q = 0; q < 4; ++q) {                                         \
            int jj = (jb) + 2 * q + esl;                                      \
            int s_ = __shfl(src, jj, 64);                                     \
            const ushort* p_ = h2 + (size_t)s_ * 128 + ch0;                   \
            asm volatile("global_load_dwordx2 %0, %1, off"                    \
                         : "=v"(u[q]) : "v"(p_));                             \
        }                                                                     \
    }
#define G2_CONS4(jb, u)                                                       \
    {                                                                         \
        _Pragma("unroll")                                                     \
        for (int q = 0; q < 4; ++q) {                                         \
            int jj = (jb) + 2 * q + esl;                                      \
            float a = alph[wave][jj];                                         \
            accA += (f32x2){a, a} * bfpair(u[q].x);                           \
            accB += (f32x2){a, a} * bfpair(u[q].y);                           \
        }                                                                     \
    }

    for (int j0 = 0; j0 < dgR; j0 += 16) {
        G2_LOAD4(j0, u1);
        G2_LOAD4(j0 + 8, u2);
        asm volatile("s_waitcnt vmcnt(0)" ::: "memory");
        __builtin_amdgcn_sched_barrier(0);
        G2_CONS4(j0, u1);
        G2_CONS4(j0 + 8, u2);
    }

    accA.x += __shfl_xor(accA.x, 32, 64); accA.y += __shfl_xor(accA.y, 32, 64);
    accB.x += __shfl_xor(accB.x, 32, 64); accB.y += __shfl_xor(accB.y, 32, 64);

    if (lane < 32) {
        const float4 bv = *(const float4*)(bias + ch0);
        const float4 fv = *(const float4*)(resid + (size_t)n * 128 + ch0);
        float4 o;
        o.x = LRELU(accA.x * rden + bv.x) + fv.x;
        o.y = LRELU(accA.y * rden + bv.y) + fv.y;
        o.z = LRELU(accB.x * rden + bv.z) + fv.z;
        o.w = LRELU(accB.y * rden + bv.w) + fv.w;
        *(float4*)(out + (size_t)n * 128 + ch0) = o;
    }
}

extern "C" void kernel_launch(void* const* d_in, const int* in_sizes, int n_in,
                              void* d_out, int out_size, void* d_ws, size_t ws_size,
                              hipStream_t stream)
{
    const float* feat = (const float*)d_in[0];
    const int*   ei   = (const int*)d_in[1];
    const float* W1   = (const float*)d_in[2];
    const float* asrc1 = (const float*)d_in[3];
    const float* adst1 = (const float*)d_in[4];
    const float* bias1 = (const float*)d_in[5];
    const float* W2    = (const float*)d_in[6];
    const float* asrc2 = (const float*)d_in[7];
    const float* adst2 = (const float*)d_in[8];
    const float* bias2 = (const float*)d_in[9];
    float* outp = (float*)d_out;

    const int IN_DIM = 128, C2 = 128;
    const int N = in_sizes[0] / IN_DIM;
    const int E = in_sizes[1] / 2;

    // workspace layout (bytes)
    char* w = (char*)d_ws;
    ushort* featb = (ushort*)w; w += (size_t)N * IN_DIM * 2;     // 12.8 MB
    ushort* aggx  = (ushort*)w; w += (size_t)4 * N * IN_DIM * 2; // 51.2 MB
    ushort* h2b   = (ushort*)w; w += (size_t)N * C2 * 2;         // 12.8 MB
    ushort* Bp1   = (ushort*)w; w += (size_t)272 * 128 * 2;
    ushort* Bp2   = (ushort*)w; w += (size_t)144 * 256 * 2;
    float* as1_   = (float*)w;  w += (size_t)N * 4 * 4;
    float* ad1_   = (float*)w;  w += (size_t)N * 4 * 4;
    float* as2_   = (float*)w;  w += (size_t)N * 4;
    float* ad2_   = (float*)w;  w += (size_t)N * 4;
    int* deg      = (int*)w;    w += (size_t)N * 4;
    ushort* col   = (ushort*)w; w += (size_t)N * 64 * 2;         // 6.4 MB padded CSR (ushort)

    dim3 blk(256);
    const int mg = (N + 63) / 64;
    const int gg = (N + 3) / 4;
    const int Npart = (N + 7) / 8;

    const int b_cvt = (N * 32 + 255) / 256;
    const int b_p1  = (272 * 128 + 255) / 256;
    const int b_p2  = (144 * 256 + 255) / 256;
    const int b_fil = 8 * ((E + 1023) / 1024);   // 8 partitions x 1024-edge chunks (dispatched first)

    hipMemsetAsync(deg, 0, (size_t)N * 4, stream);
    prep_kernel<<<dim3(b_fil + b_cvt + b_p1 + b_p2), blk, 0, stream>>>(
        feat, W1, asrc1, adst1, W2, asrc2, adst2, ei,
        featb, Bp1, Bp2, deg, col, N, E, Npart, b_fil, b_cvt, b_p1);

    // ---- layer 1: composites -> x-space gather ----
    gemm_attn1_kernel<<<dim3(mg), blk, 0, stream>>>(featb, Bp1, as1_, ad1_, N);
    gat_gather1_kernel<<<dim3(gg), blk, 0, stream>>>(deg, col, as1_, ad1_, featb, aggx, N);

    // ---- fused per-head GEMM + layer-2 GEMM (x1 internal to LDS) ----
    gemm_l1l2_kernel<<<dim3(mg), blk, 0, stream>>>(aggx, Bp1, bias1, Bp2, h2b, as2_, ad2_, N);

    // ---- layer-2 gather + residual ----
    gat_gather2_kernel<<<dim3(gg), blk, 0, stream>>>(deg, col, as2_, ad2_, h2b, bias2, feat, outp, N);
}